// Round 15
// baseline (30.703 us; speedup 1.0000x reference)
//
#include <hip/hip_runtime.h>
#include <math.h>

#define B_ 4
#define N_ 32768
#define M_ 8192
#define K_ 16
#define D_ 64
#define O_ 64

typedef __attribute__((ext_vector_type(8))) short bf16x8;
typedef __attribute__((ext_vector_type(4))) float f32x4;

// float -> bf16 bits, round-to-nearest-even (inputs are finite normals)
static __device__ __forceinline__ short f2bf(float f) {
    unsigned u = __float_as_uint(f);
    u += 0x7fffu + ((u >> 16) & 1u);
    return (short)(u >> 16);
}

static __device__ __forceinline__ bf16x8 cvt_bf8(float4 f0, float4 f1) {
    bf16x8 v;
    v[0] = f2bf(f0.x); v[1] = f2bf(f0.y); v[2] = f2bf(f0.z); v[3] = f2bf(f0.w);
    v[4] = f2bf(f1.x); v[5] = f2bf(f1.y); v[6] = f2bf(f1.z); v[7] = f2bf(f1.w);
    return v;
}

// 8 consecutive floats -> bf16x8 (one MFMA k-chunk)
static __device__ __forceinline__ bf16x8 ld_bf8(const float* p) {
    return cvt_bf8(*(const float4*)p, *(const float4*)(p + 4));
}

// keep a loaded float4 alive via scalar-component pins (float4 itself is a
// multi-reg value clang's asm "v" constraint rejects)
#define PIN4(q) asm volatile("" :: "v"((q).x), "v"((q).y), "v"((q).z), "v"((q).w))

// ---------------------------------------------------------------------------
// Fused kernel (R15 = R14 with compilable pins — trade ILP heroics for TLP):
//   out[b,o,m] = relu( max_k (x[b,idx[m,k]].W1[o]) + xs[b,m].(W2-W1)[o] + b[o] )
// R13 evidence: VGPR=76 -> asm pipeline shared dest regs, scoreboard
// serialized it. R8's gather_max proved 13 TB/s through this path with PURE
// TLP (8 waves/SIMD, zero ILP). R14/R15: 1024 blocks x 512 thr (8 waves,
// wave = 4 m) = 8192 waves (4x R13).
//  - W frags via LDS (wave wv stages slice t=wv>>1, s=wv&1); re-read per
//    use to keep VGPR low (off the gather critical path).
//  - all 16 gather loads issued up front, pinned by empty asm uses on
//    scalar components (prevents R12-style sinking).
//  - all 32 shfl reductions AFTER the MFMA block (DS in-order completion
//    can't stall MFMAs — R10 lesson).
//  - batch-affine XCD swizzle: batch <-> XCD pair, x/batch 8.4MB over 2 L2s.
// ---------------------------------------------------------------------------
__global__ __launch_bounds__(512, 4)
void fused_gconv(const float* __restrict__ x, const float* __restrict__ xs,
                 const int* __restrict__ idx, const float* __restrict__ W,
                 const float* __restrict__ bias, float* __restrict__ out) {
    __shared__ int    ldsI[512];             // 32 m x 16 k
    __shared__ bf16x8 ldsW[4][2][2][64];     // 16 KB: [t][s][b1/bd][lane]
    __shared__ float  ldsB[64];
    __shared__ float  ldsT[64 * 33];         // [o][m] transpose

    const int tid  = threadIdx.x;
    const int blk  = blockIdx.x;       // 0..1023
    const int xcd  = blk & 7;
    const int slot = blk >> 3;         // 0..127
    const int bb   = xcd >> 1;         // batch on XCD pair {2c,2c+1}
    const int m0   = (((xcd & 1) << 7) + slot) << 5;   // batch-local m base

    // stage idx: 2KB, fully coalesced
    ldsI[tid] = idx[((size_t)bb * M_ + m0) * 16 + tid];

    const int l  = tid & 63;
    const int wv = tid >> 6;           // 0..7; m-group = wv*4..wv*4+3
    const int lr = l & 15;
    const int kg = l >> 4;

    // ---- W-frag stage: wave wv converts slice t = wv>>1, s = wv&1
    {
        const int t = wv >> 1, s = wv & 1;
        const float* wp = W + (size_t)(t * 16 + lr) * 128 + s * 32 + kg * 8;
        float4 f0 = *(const float4*)wp;
        float4 f1 = *(const float4*)(wp + 4);
        float4 g0 = *(const float4*)(wp + 64);
        float4 g1 = *(const float4*)(wp + 68);
        ldsW[t][s][0][l] = cvt_bf8(f0, f1);
        float4 d0 = make_float4(g0.x - f0.x, g0.y - f0.y, g0.z - f0.z, g0.w - f0.w);
        float4 d1 = make_float4(g1.x - f1.x, g1.y - f1.y, g1.z - f1.z, g1.w - f1.w);
        ldsW[t][s][1][l] = cvt_bf8(d0, d1);
        if (tid < 64) ldsB[tid] = bias[tid];
    }
    __syncthreads();

    float binit[4];
    #pragma unroll
    for (int t = 0; t < 4; ++t) binit[t] = ldsB[t * 16 + lr];

    // ---- center: wave's 16-row xs tile (tile wv>>2) vs (W2-W1), bias-init.
    // D rows kg*4+r; owner lanes kg == (wv&3) hold this wave's m = wv*4+r.
    const float* xsp = xs + ((size_t)bb * M_ + m0 + (wv >> 2) * 16 + lr) * 64 + kg * 8;
    bf16x8 axs0 = ld_bf8(xsp);
    bf16x8 axs1 = ld_bf8(xsp + 32);

    float vout[4][4];                  // [t][r]
    #pragma unroll
    for (int t = 0; t < 4; ++t) {
        bf16x8 bd0 = ldsW[t][0][1][l];
        bf16x8 bd1 = ldsW[t][1][1][l];
        f32x4 a = {binit[t], binit[t], binit[t], binit[t]};
        a = __builtin_amdgcn_mfma_f32_16x16x32_bf16(axs0, bd0, a, 0, 0, 0);
        a = __builtin_amdgcn_mfma_f32_16x16x32_bf16(axs1, bd1, a, 0, 0, 0);
        vout[t][0] = a[0]; vout[t][1] = a[1];
        vout[t][2] = a[2]; vout[t][3] = a[3];
    }

    // ---- hoist this wave's 4 idx rows
    int rr[4];
    #pragma unroll
    for (int j = 0; j < 4; ++j)
        rr[j] = ldsI[(wv * 4 + j) * 16 + lr];

    const float* xb = x + (size_t)bb * N_ * 64;

    // ---- issue ALL 16 gather loads up front, then pin (no sinking)
    float4 q0[4], q1[4], q2[4], q3[4];
    #pragma unroll
    for (int j = 0; j < 4; ++j) {
        const float* xp = xb + (size_t)(unsigned)rr[j] * 64 + kg * 8;
        q0[j] = *(const float4*)xp;
        q1[j] = *(const float4*)(xp + 4);
        q2[j] = *(const float4*)(xp + 32);
        q3[j] = *(const float4*)(xp + 36);
    }
    #pragma unroll
    for (int j = 0; j < 4; ++j) {
        PIN4(q0[j]); PIN4(q1[j]); PIN4(q2[j]); PIN4(q3[j]);
    }

    // convert once; a-frags reused across the t-loop
    bf16x8 a0[4], a1[4];
    #pragma unroll
    for (int j = 0; j < 4; ++j) {
        a0[j] = cvt_bf8(q0[j], q1[j]);
        a1[j] = cvt_bf8(q2[j], q3[j]);
    }

    // ---- MFMA block: 32 MFMAs back-to-back; reductions deferred
    float pv[4][4];                    // [t][j] in-lane partial max
    #pragma unroll
    for (int t = 0; t < 4; ++t) {
        bf16x8 w0 = ldsW[t][0][0][l];
        bf16x8 w1 = ldsW[t][1][0][l];
        #pragma unroll
        for (int j = 0; j < 4; ++j) {
            f32x4 a = {0.f, 0.f, 0.f, 0.f};
            a = __builtin_amdgcn_mfma_f32_16x16x32_bf16(a0[j], w0, a, 0, 0, 0);
            a = __builtin_amdgcn_mfma_f32_16x16x32_bf16(a1[j], w1, a, 0, 0, 0);
            pv[t][j] = fmaxf(fmaxf(a[0], a[1]), fmaxf(a[2], a[3]));
        }
    }

    // ---- deferred cross-lane max (32 bpermutes, nothing downstream but adds)
    #pragma unroll
    for (int t = 0; t < 4; ++t)
        #pragma unroll
        for (int j = 0; j < 4; ++j) {
            float v = pv[t][j];
            v = fmaxf(v, __shfl_xor(v, 16));
            v = fmaxf(v, __shfl_xor(v, 32));
            if (kg == (wv & 3))        // owner lane-group
                vout[t][j] += v;
        }

    // relu + transpose write (owner lanes): [o = t*16+lr][m = wv*4 + r]
    if (kg == (wv & 3)) {
        #pragma unroll
        for (int t = 0; t < 4; ++t)
            #pragma unroll
            for (int r = 0; r < 4; ++r) {
                float v = vout[t][r];
                ldsT[(t * 16 + lr) * 33 + wv * 4 + r] = v > 0.f ? v : 0.f;
            }
    }
    __syncthreads();

    // coalesced stores: thread tid -> o = tid>>3, 4 m at (tid&7)*4
    const int o  = tid >> 3;
    const int ms = (tid & 7) * 4;
    const float* lp = &ldsT[o * 33 + ms];
    float4 v = make_float4(lp[0], lp[1], lp[2], lp[3]);
    *(float4*)(out + ((size_t)bb * 64 + o) * M_ + m0 + ms) = v;
}

extern "C" void kernel_launch(void* const* d_in, const int* in_sizes, int n_in,
                              void* d_out, int out_size, void* d_ws, size_t ws_size,
                              hipStream_t stream) {
    const float* x    = (const float*)d_in[0];
    const float* xs   = (const float*)d_in[1];
    const int*   idx  = (const int*)d_in[2];
    const float* W    = (const float*)d_in[3];
    const float* bias = (const float*)d_in[4];
    float* out = (float*)d_out;

    // 1024 blocks x 512 thr; block = 32 m, wave = 4 m
    fused_gconv<<<(B_ * M_) / 32, 512, 0, stream>>>(x, xs, idx, W, bias, out);
}